// Round 10
// baseline (103.638 us; speedup 1.0000x reference)
//
#include <hip/hip_runtime.h>

#define B_ 32
#define L_ 1024
#define D_ 128
#define NT 512

typedef __attribute__((ext_vector_type(8))) short bf8_t;
typedef __attribute__((ext_vector_type(4))) float f4_t;

__device__ __forceinline__ unsigned cvtpk(float lo, float hi) {
  unsigned r;
  asm("v_cvt_pk_bf16_f32 %0, %1, %2" : "=v"(r) : "v"(lo), "v"(hi));
  return r;
}

__device__ __forceinline__ void gload16(const void* g, void* l) {
  __builtin_amdgcn_global_load_lds((const __attribute__((address_space(1))) void*)g,
                                   (__attribute__((address_space(3))) void*)l, 16, 0, 0);
}

// Prologue: pre-swizzled bf16 X panels + sq + channel-0 copy + W in
// fragment-coalesced layout Wc[which][j/32][d][j%32] (bf16).
__global__ __launch_bounds__(256)
void prep_kernel(const float* __restrict__ x0, const float* __restrict__ x1,
                 const float* __restrict__ W0, const float* __restrict__ W1,
                 short* __restrict__ Xs, float* __restrict__ sq,
                 short* __restrict__ Wt, float* __restrict__ out) {
  int bid = blockIdx.x;
  if (bid < 8192) {
    int t = bid * 256 + threadIdx.x;     // 0 .. 2097151
    int row_id = t >> 5;                 // (which,b,row)
    int qp = t & 31;
    int which = row_id >> 15;
    int b = (row_id >> 10) & 31;
    int row = row_id & 1023;
    const float* x = which ? x1 : x0;
    float4 v = *(const float4*)(x + ((size_t)b * L_ + row) * D_ + qp * 4);
    float* o = out + (size_t)which * (B_ * 2 * L_ * D_) + (size_t)b * (2 * L_ * D_)
             + (size_t)row * D_ + qp * 4;
    *(float4*)o = v;
    unsigned w0 = cvtpk(v.x, v.y), w1 = cvtpk(v.z, v.w);
    char* xb = (char*)Xs + (size_t)row_id * 256 + ((qp * 8) ^ ((row & 7) << 4));
    *(uint2*)xb = make_uint2(w0, w1);
    float s = v.x * v.x + v.y * v.y + v.z * v.z + v.w * v.w;
    s += __shfl_xor(s, 1); s += __shfl_xor(s, 2); s += __shfl_xor(s, 4);
    s += __shfl_xor(s, 8); s += __shfl_xor(s, 16);
    if (qp == 0) sq[row_id] = s;
  } else {
    int idx = (bid - 8192) * 256 + threadIdx.x;  // 0..262143
    int which = idx >> 17;
    int rm = idx & 131071;
    int j32 = rm >> 12;       // 32 tiles of 32 j
    int d = (rm >> 5) & 127;
    int jj = rm & 31;
    const float* W = which ? W1 : W0;
    float wv = W[(j32 * 32 + jj) * D_ + d];
    Wt[idx] = (short)(cvtpk(wv, wv) & 0xffffu);
  }
}

__global__ __launch_bounds__(NT, 6)
void fused_attnconv(const short* __restrict__ Xs, const float* __restrict__ sq,
                    const short* __restrict__ Wt, float* __restrict__ out) {
  // LDS: [0,8K) y0 [8K,16K) y1 [16K,24K) P0 [24K,32K) P1 [32K,36K) sqy
  __shared__ char smem[36864];
  char* Pbase = smem + 16384;
  float* sqyL = (float*)(smem + 32768);

  const int bid = blockIdx.x;
  const int x = bid & 7, g = bid >> 3;
  const int p = x + 8 * (g >> 4);       // panel id = which*32+b
  const int it = g & 15;                // i-tile (64 rows)
  const int which = p >> 5, b = p & 31;
  const int i0 = it * 64;
  const int po = (which ^ 1) * 32 + b;  // opposite tensor: y-side

  const char* apanel = (const char*)Xs + (size_t)p * (L_ * 256);
  const char* ypanel = (const char*)Xs + (size_t)po * (L_ * 256);
  const float* sqx_p = sq + p * L_;
  const float* sqy_p = sq + po * L_;
  float* Oc1 = out + (size_t)which * (B_ * 2 * L_ * D_) + (size_t)b * (2 * L_ * D_) + (L_ * D_);

  const int tid = threadIdx.x;
  const int lane = tid & 63;
  const int w = tid >> 6;
  const int l15 = lane & 15;
  const int q = lane >> 4;
  const int wr = w & 3;           // i-strip: rows I0..I0+15
  const int wc = w >> 2;          // MFMA-1: j-quadrant; MFMA-2: d-half
  const int I0 = wr * 16;
  const int JS = wc * 16;         // j-offset within 32-wide tile
  const int D0 = wc * 64;         // d-half for output
  const int swz = (l15 & 7) << 4;

  // a-fragments in registers (global Xs is pre-swizzled -> apply same XOR)
  bf8_t afr[4];
#pragma unroll
  for (int kb = 0; kb < 4; ++kb)
    afr[kb] = *(const bf8_t*)(apanel + (size_t)(i0 + I0 + l15) * 256 + ((kb * 64 + q * 16) ^ swz));
  const float sxv = sqx_p[i0 + I0 + l15];

  // stage sqy (4 KB, once) + y-tile 0 (8 KB)
  if (tid < 256) {
    *(f4_t*)(sqyL + tid * 4) = *(const f4_t*)(sqy_p + tid * 4);
  }
  gload16(ypanel + tid * 16, smem + tid * 16);

  f4_t z4 = {0.f, 0.f, 0.f, 0.f};
  f4_t acc[4] = {z4, z4, z4, z4};

  __syncthreads();  // vmcnt(0)+lgkm drained: tile 0 + sqy staged

  for (int jt = 0; jt < 32; ++jt) {
    const int cur = jt & 1;
    char* yB = smem + cur * 8192;
    char* Pw = Pbase + cur * 8192;

    // 1) prefetch next y-tile (8 KB, 1 gload16/thread)
    if (jt < 31)
      gload16(ypanel + (jt + 1) * 8192 + tid * 16, smem + (1 - cur) * 8192 + tid * 16);

    // 2) W fragments -> regs (global, L2-hot, contiguous 1KB per load)
    const short* Wb = Wt + which * 131072 + jt * 4096;
    bf8_t wf[4];
#pragma unroll
    for (int m = 0; m < 4; ++m)
      wf[m] = *(const bf8_t*)(Wb + (D0 + m * 16 + l15) * 32 + q * 8);

    // 3) sy for this wave's j-quadrant (LDS, mostly-broadcast)
    f4_t sy = *(const f4_t*)(sqyL + jt * 32 + JS + q * 4);

    // 4) MFMA-1 (swapped): ST = y . a^T over (i: I0+l15, j: JS+q*4+r)
    f4_t ST = z4;
#pragma unroll
    for (int kb = 0; kb < 4; ++kb) {
      const int kc = (kb * 64 + q * 16) ^ swz;
      bf8_t yf = *(const bf8_t*)(yB + (JS + l15) * 256 + kc);
      ST = __builtin_amdgcn_mfma_f32_16x16x32_bf16(yf, afr[kb], ST, 0, 0, 0);
    }

    // 5) elementwise A = 1/(1+dist) -> P[cur] quadrant (16i x 16j)
    {
      float A0 = __builtin_amdgcn_rcpf(1.0f + __builtin_amdgcn_sqrtf(fmaxf(__builtin_fmaf(-2.f, ST[0], sxv + sy[0]), 0.f)));
      float A1 = __builtin_amdgcn_rcpf(1.0f + __builtin_amdgcn_sqrtf(fmaxf(__builtin_fmaf(-2.f, ST[1], sxv + sy[1]), 0.f)));
      float A2 = __builtin_amdgcn_rcpf(1.0f + __builtin_amdgcn_sqrtf(fmaxf(__builtin_fmaf(-2.f, ST[2], sxv + sy[2]), 0.f)));
      float A3 = __builtin_amdgcn_rcpf(1.0f + __builtin_amdgcn_sqrtf(fmaxf(__builtin_fmaf(-2.f, ST[3], sxv + sy[3]), 0.f)));
      *(uint2*)(Pw + (I0 + l15) * 128 + ((JS * 2 + q * 8) ^ swz)) =
          make_uint2(cvtpk(A0, A1), cvtpk(A2, A3));
    }

    __syncthreads();  // P[cur] complete block-wide; y(t+1) staged

    // 6) MFMA-2: acc[m] += P(rows I0..) . W ; full K=32, d-half split by wc
    bf8_t pf = *(const bf8_t*)(Pw + (I0 + l15) * 128 + ((q * 16) ^ swz));
#pragma unroll
    for (int m = 0; m < 4; ++m)
      acc[m] = __builtin_amdgcn_mfma_f32_16x16x32_bf16(pf, wf[m], acc[m], 0, 0, 0);
  }

  // epilogue: direct store (no cross-wave reduction; wc owns d-half)
#pragma unroll
  for (int m = 0; m < 4; ++m) {
    const int d = D0 + m * 16 + l15;
#pragma unroll
    for (int r = 0; r < 4; ++r)
      Oc1[(size_t)(i0 + I0 + q * 4 + r) * D_ + d] = acc[m][r];
  }
}

extern "C" void kernel_launch(void* const* d_in, const int* in_sizes, int n_in,
                              void* d_out, int out_size, void* d_ws, size_t ws_size,
                              hipStream_t stream) {
  const float* x0 = (const float*)d_in[0];
  const float* x1 = (const float*)d_in[1];
  const float* W0 = (const float*)d_in[2];
  const float* W1 = (const float*)d_in[3];
  float* out = (float*)d_out;

  char* ws = (char*)d_ws;
  short* Wt = (short*)ws;                       // 512 KB, fragment-coalesced layout
  short* Xs = (short*)(ws + 524288);            // 16.78 MB, pre-swizzled bf16
  float* sq = (float*)(ws + 524288 + 16777216); // 256 KB

  prep_kernel<<<9216, 256, 0, stream>>>(x0, x1, W0, W1, Xs, sq, Wt, out);
  fused_attnconv<<<1024, NT, 0, stream>>>(Xs, sq, Wt, out);
}